// Round 1
// baseline (706.855 us; speedup 1.0000x reference)
//
#include <hip/hip_runtime.h>
#include <hip/hip_bf16.h>

#define N_NODES 100000
#define N_EDGES 640000
#define D 128
#define BN_EPS 1e-5f

// ---------------- init: deg=1 (self-loop), stats=0 ----------------
__global__ void k_init(float* __restrict__ deg, float* __restrict__ stats) {
    int i = blockIdx.x * 256 + threadIdx.x;
    if (i < N_NODES) deg[i] = 1.0f;
    if (i < 256) stats[i] = 0.0f;
}

// ---------------- degree count over dst ----------------
__global__ void k_deg(const int* __restrict__ ei, float* __restrict__ deg) {
    int e = blockIdx.x * 256 + threadIdx.x;
    if (e < N_EDGES) {
        int d = ei[N_EDGES + e];  // dst = edge_index[1][e]
        atomicAdd(&deg[d], 1.0f);
    }
}

// ---------------- dinv = rsqrt(deg) in place ----------------
__global__ void k_rsqrt(float* __restrict__ deg) {
    int i = blockIdx.x * 256 + threadIdx.x;
    if (i < N_NODES) deg[i] = rsqrtf(deg[i]);
}

// ---------------- GEMM h = x@W; epilogue: out = h*dinv^2 + b (self-loop + bias) ----------------
#define GM_ROWS 32
__global__ __launch_bounds__(256) void k_gemm(const float* __restrict__ x,
                                              const float* __restrict__ W,
                                              const float* __restrict__ b,
                                              const float* __restrict__ dinv,
                                              float* __restrict__ h,
                                              float* __restrict__ out) {
    __shared__ float xs[GM_ROWS][D];  // 16 KB
    const int r0 = blockIdx.x * GM_ROWS;
    const int t = threadIdx.x;

    // cooperative load of up to 32 rows of x (float4-vectorized, coalesced)
    int nrows = N_NODES - r0; if (nrows > GM_ROWS) nrows = GM_ROWS;
    const float4* xg = (const float4*)(x + (size_t)r0 * D);
    float4* xsv = (float4*)(&xs[0][0]);
    const int nvec = nrows * (D / 4);
    for (int i = t; i < nvec; i += 256) xsv[i] = xg[i];
    __syncthreads();

    const int d = t & 127;       // output column
    const int rg = t >> 7;       // row-group 0..1
    const int rbase = rg * 16;

    float acc[16];
#pragma unroll
    for (int i = 0; i < 16; ++i) acc[i] = 0.0f;

    for (int k0 = 0; k0 < D; k0 += 4) {
        float w0 = W[(k0 + 0) * D + d];
        float w1 = W[(k0 + 1) * D + d];
        float w2 = W[(k0 + 2) * D + d];
        float w3 = W[(k0 + 3) * D + d];
#pragma unroll
        for (int i = 0; i < 16; ++i) {
            float4 xv = *(const float4*)&xs[rbase + i][k0];
            acc[i] = fmaf(xv.x, w0, acc[i]);
            acc[i] = fmaf(xv.y, w1, acc[i]);
            acc[i] = fmaf(xv.z, w2, acc[i]);
            acc[i] = fmaf(xv.w, w3, acc[i]);
        }
    }

    const float bd = b[d];
#pragma unroll
    for (int i = 0; i < 16; ++i) {
        int n = r0 + rbase + i;
        if (n < N_NODES) {
            float hv = acc[i];
            h[(size_t)n * D + d] = hv;
            float di = dinv[n];
            out[(size_t)n * D + d] = fmaf(hv, di * di, bd);
        }
    }
}

// ---------------- edge scatter: out[dst] += h[src] * dinv[src]*dinv[dst] ----------------
// one wave (64 lanes) per edge, float2 per lane; 4 edges per 256-thread block
__global__ __launch_bounds__(256) void k_scatter(const int* __restrict__ ei,
                                                 const float* __restrict__ h,
                                                 const float* __restrict__ dinv,
                                                 float* __restrict__ out) {
    const int t = threadIdx.x;
    const int lane = t & 63;
    const int e = blockIdx.x * 4 + (t >> 6);
    if (e >= N_EDGES) return;
    const int s = ei[e];
    const int dn = ei[N_EDGES + e];
    const float norm = dinv[s] * dinv[dn];
    const float2 v = ((const float2*)(h + (size_t)s * D))[lane];
    float* orow = out + (size_t)dn * D + lane * 2;
    atomicAdd(orow, v.x * norm);
    atomicAdd(orow + 1, v.y * norm);
}

// ---------------- BN stats: per-channel sum & sumsq of relu(agg) ----------------
__global__ __launch_bounds__(256) void k_stats(const float* __restrict__ agg,
                                               float* __restrict__ stats) {
    const int t = threadIdx.x;
    const int c = t & 127;
    const int half = t >> 7;
    float s = 0.0f, s2 = 0.0f;
    for (int r = blockIdx.x * 2 + half; r < N_NODES; r += gridDim.x * 2) {
        float v = agg[(size_t)r * D + c];
        v = fmaxf(v, 0.0f);
        s += v;
        s2 = fmaf(v, v, s2);
    }
    __shared__ float ls[256], ls2[256];
    ls[t] = s; ls2[t] = s2;
    __syncthreads();
    if (t < 128) {
        atomicAdd(&stats[c], ls[t] + ls[t + 128]);
        atomicAdd(&stats[128 + c], ls2[t] + ls2[t + 128]);
    }
}

// ---------------- normalize in place: gamma*(relu(v)-mean)*rsqrt(var+eps)+beta ----------------
__global__ __launch_bounds__(256) void k_norm(float* __restrict__ io,
                                              const float* __restrict__ stats,
                                              const float* __restrict__ gamma,
                                              const float* __restrict__ beta) {
    const size_t i = (size_t)blockIdx.x * 256 + threadIdx.x;
    if (i >= (size_t)N_NODES * D) return;
    const int c = (int)(i & 127);
    const float inv_n = 1.0f / (float)N_NODES;
    const float mean = stats[c] * inv_n;
    const float var = stats[128 + c] * inv_n - mean * mean;
    const float v = fmaxf(io[i], 0.0f);
    io[i] = fmaf(gamma[c] * rsqrtf(var + BN_EPS), v - mean, beta[c]);
}

extern "C" void kernel_launch(void* const* d_in, const int* in_sizes, int n_in,
                              void* d_out, int out_size, void* d_ws, size_t ws_size,
                              hipStream_t stream) {
    const float* x     = (const float*)d_in[0];
    const int*   ei    = (const int*)d_in[1];   // [2][E]: src then dst
    const float* W     = (const float*)d_in[2];
    const float* b     = (const float*)d_in[3];
    const float* gamma = (const float*)d_in[4];
    const float* beta  = (const float*)d_in[5];
    float* out = (float*)d_out;

    // workspace layout
    float* deg   = (float*)d_ws;                               // N floats (becomes dinv)
    float* stats = (float*)((char*)d_ws + (512u * 1024u));     // 256 floats
    float* h     = (float*)((char*)d_ws + (1024u * 1024u));    // N*D floats = 51.2 MB

    const int nblk_n = (N_NODES + 255) / 256;     // 391
    const int nblk_e = (N_EDGES + 255) / 256;     // 2500

    k_init<<<nblk_n, 256, 0, stream>>>(deg, stats);
    k_deg<<<nblk_e, 256, 0, stream>>>(ei, deg);
    k_rsqrt<<<nblk_n, 256, 0, stream>>>(deg);
    k_gemm<<<(N_NODES + GM_ROWS - 1) / GM_ROWS, 256, 0, stream>>>(x, W, b, deg, h, out);
    k_scatter<<<(N_EDGES + 3) / 4, 256, 0, stream>>>(ei, h, deg, out);
    k_stats<<<512, 256, 0, stream>>>(out, stats);
    k_norm<<<(N_NODES * D + 255) / 256, 256, 0, stream>>>(out, stats, gamma, beta);
}

// Round 2
// 286.886 us; speedup vs baseline: 2.4639x; 2.4639x over previous
//
#include <hip/hip_runtime.h>
#include <hip/hip_bf16.h>

#define N_NODES 100000
#define N_EDGES 640000
#define D 128
#define BN_EPS 1e-5f
#define NB_SCAN 98  // ceil(100000/1024)

// ---------------- zero counters ----------------
__global__ void k_zero(int* __restrict__ cnt, int* __restrict__ fill, float* __restrict__ stats) {
    int i = blockIdx.x * 256 + threadIdx.x;
    if (i < N_NODES) { cnt[i] = 0; fill[i] = 0; }
    if (i < 256) stats[i] = 0.0f;
}

// ---------------- count incoming edges per dst ----------------
__global__ void k_cnt(const int* __restrict__ ei, int* __restrict__ cnt) {
    int e = blockIdx.x * 256 + threadIdx.x;
    if (e < N_EDGES) atomicAdd(&cnt[ei[N_EDGES + e]], 1);
}

// ---------------- scan stage 1: per-1024-block exclusive scan ----------------
__global__ __launch_bounds__(1024) void k_scan1(const int* __restrict__ cnt,
                                                int* __restrict__ off,
                                                int* __restrict__ bsum) {
    __shared__ int s[1024];
    const int t = threadIdx.x;
    const int i = blockIdx.x * 1024 + t;
    const int v = (i < N_NODES) ? cnt[i] : 0;
    s[t] = v;
    __syncthreads();
    for (int d = 1; d < 1024; d <<= 1) {
        int u = (t >= d) ? s[t - d] : 0;
        __syncthreads();
        s[t] += u;
        __syncthreads();
    }
    if (i < N_NODES) off[i] = s[t] - v;  // exclusive
    if (t == 1023) bsum[blockIdx.x] = s[t];
}

// ---------------- scan stage 2: scan the 98 block sums ----------------
__global__ __launch_bounds__(128) void k_scan2(int* __restrict__ bsum) {
    __shared__ int s[128];
    const int t = threadIdx.x;
    const int v = (t < NB_SCAN) ? bsum[t] : 0;
    s[t] = v;
    __syncthreads();
    for (int d = 1; d < 128; d <<= 1) {
        int u = (t >= d) ? s[t - d] : 0;
        __syncthreads();
        s[t] += u;
        __syncthreads();
    }
    if (t < NB_SCAN) bsum[t] = s[t] - v;  // exclusive
}

// ---------------- scan stage 3: add block offsets; compute dinv ----------------
__global__ void k_scan3(int* __restrict__ off, const int* __restrict__ bsum,
                        const int* __restrict__ cnt, float* __restrict__ dinv) {
    const int i = blockIdx.x * 256 + threadIdx.x;
    if (i < N_NODES) {
        off[i] += bsum[i >> 10];
        dinv[i] = rsqrtf((float)(cnt[i] + 1));  // +1 self-loop
    }
    if (i == 0) off[N_NODES] = N_EDGES;
}

// ---------------- fill CSR: bucket src by dst ----------------
__global__ void k_fill(const int* __restrict__ ei, const int* __restrict__ off,
                       int* __restrict__ fill, int* __restrict__ csr) {
    int e = blockIdx.x * 256 + threadIdx.x;
    if (e < N_EDGES) {
        int d = ei[N_EDGES + e];
        int slot = atomicAdd(&fill[d], 1);
        csr[off[d] + slot] = ei[e];
    }
}

// ---------------- GEMM h = x@W ----------------
#define GM_ROWS 32
__global__ __launch_bounds__(256) void k_gemm(const float* __restrict__ x,
                                              const float* __restrict__ W,
                                              float* __restrict__ h) {
    __shared__ float xs[GM_ROWS][D];  // 16 KB
    const int r0 = blockIdx.x * GM_ROWS;
    const int t = threadIdx.x;

    int nrows = N_NODES - r0; if (nrows > GM_ROWS) nrows = GM_ROWS;
    const float4* xg = (const float4*)(x + (size_t)r0 * D);
    float4* xsv = (float4*)(&xs[0][0]);
    const int nvec = nrows * (D / 4);
    for (int i = t; i < nvec; i += 256) xsv[i] = xg[i];
    __syncthreads();

    const int d = t & 127;
    const int rbase = (t >> 7) * 16;

    float acc[16];
#pragma unroll
    for (int i = 0; i < 16; ++i) acc[i] = 0.0f;

    for (int k0 = 0; k0 < D; k0 += 4) {
        float w0 = W[(k0 + 0) * D + d];
        float w1 = W[(k0 + 1) * D + d];
        float w2 = W[(k0 + 2) * D + d];
        float w3 = W[(k0 + 3) * D + d];
#pragma unroll
        for (int i = 0; i < 16; ++i) {
            float4 xv = *(const float4*)&xs[rbase + i][k0];
            acc[i] = fmaf(xv.x, w0, acc[i]);
            acc[i] = fmaf(xv.y, w1, acc[i]);
            acc[i] = fmaf(xv.z, w2, acc[i]);
            acc[i] = fmaf(xv.w, w3, acc[i]);
        }
    }

#pragma unroll
    for (int i = 0; i < 16; ++i) {
        int n = r0 + rbase + i;
        if (n < N_NODES) h[(size_t)n * D + d] = acc[i];
    }
}

// ---------------- gather: one wave per dst node ----------------
// acc = h[n]*dinv[n]^2 + b + sum_{s in csr[n]} h[s]*dinv[s]*dinv[n];  relu fused
__global__ __launch_bounds__(256) void k_gather(const int* __restrict__ csr,
                                                const int* __restrict__ off,
                                                const float* __restrict__ h,
                                                const float* __restrict__ dinv,
                                                const float* __restrict__ b,
                                                float* __restrict__ out) {
    const int t = threadIdx.x;
    const int lane = t & 63;
    const int n = blockIdx.x * 4 + (t >> 6);
    if (n >= N_NODES) return;

    const float di = dinv[n];
    const float2 hv = ((const float2*)(h + (size_t)n * D))[lane];
    const float2 bb = ((const float2*)b)[lane];
    float ax = fmaf(hv.x, di * di, bb.x);
    float ay = fmaf(hv.y, di * di, bb.y);

    const int j0 = off[n], j1 = off[n + 1];
    for (int j = j0; j < j1; ++j) {
        const int s = csr[j];
        const float norm = dinv[s] * di;
        const float2 v = ((const float2*)(h + (size_t)s * D))[lane];
        ax = fmaf(v.x, norm, ax);
        ay = fmaf(v.y, norm, ay);
    }
    ax = fmaxf(ax, 0.0f);
    ay = fmaxf(ay, 0.0f);
    ((float2*)(out + (size_t)n * D))[lane] = make_float2(ax, ay);
}

// ---------------- BN stats (input already relu'd) ----------------
__global__ __launch_bounds__(256) void k_stats(const float* __restrict__ agg,
                                               float* __restrict__ stats) {
    const int t = threadIdx.x;
    const int c = t & 127;
    const int half = t >> 7;
    float s = 0.0f, s2 = 0.0f;
    for (int r = blockIdx.x * 2 + half; r < N_NODES; r += gridDim.x * 2) {
        float v = agg[(size_t)r * D + c];
        s += v;
        s2 = fmaf(v, v, s2);
    }
    __shared__ float ls[256], ls2[256];
    ls[t] = s; ls2[t] = s2;
    __syncthreads();
    if (t < 128) {
        atomicAdd(&stats[c], ls[t] + ls[t + 128]);
        atomicAdd(&stats[128 + c], ls2[t] + ls2[t + 128]);
    }
}

// ---------------- normalize in place (input already relu'd) ----------------
__global__ __launch_bounds__(256) void k_norm(float* __restrict__ io,
                                              const float* __restrict__ stats,
                                              const float* __restrict__ gamma,
                                              const float* __restrict__ beta) {
    const size_t i = (size_t)blockIdx.x * 256 + threadIdx.x;
    if (i >= (size_t)N_NODES * D) return;
    const int c = (int)(i & 127);
    const float inv_n = 1.0f / (float)N_NODES;
    const float mean = stats[c] * inv_n;
    const float var = stats[128 + c] * inv_n - mean * mean;
    const float v = io[i];
    io[i] = fmaf(gamma[c] * rsqrtf(var + BN_EPS), v - mean, beta[c]);
}

extern "C" void kernel_launch(void* const* d_in, const int* in_sizes, int n_in,
                              void* d_out, int out_size, void* d_ws, size_t ws_size,
                              hipStream_t stream) {
    const float* x     = (const float*)d_in[0];
    const int*   ei    = (const int*)d_in[1];   // [2][E]: src then dst
    const float* W     = (const float*)d_in[2];
    const float* b     = (const float*)d_in[3];
    const float* gamma = (const float*)d_in[4];
    const float* beta  = (const float*)d_in[5];
    float* out = (float*)d_out;

    // workspace layout (bytes)
    char* ws = (char*)d_ws;
    int*   cnt   = (int*)(ws + 0);                 // N ints
    int*   fill  = (int*)(ws + (512u << 10));      // N ints
    int*   off   = (int*)(ws + (1024u << 10));     // N+1 ints
    int*   bsum  = (int*)(ws + (1536u << 10));     // 98 ints
    float* dinv  = (float*)(ws + (1792u << 10));   // N floats
    float* stats = (float*)(ws + (2304u << 10));   // 256 floats
    int*   csr   = (int*)(ws + (2560u << 10));     // E ints (2.56 MB)
    float* h     = (float*)(ws + (8192u << 10));   // N*D floats = 51.2 MB

    const int nblk_n = (N_NODES + 255) / 256;   // 391
    const int nblk_e = (N_EDGES + 255) / 256;   // 2500

    k_zero<<<nblk_n, 256, 0, stream>>>(cnt, fill, stats);
    k_cnt<<<nblk_e, 256, 0, stream>>>(ei, cnt);
    k_scan1<<<NB_SCAN, 1024, 0, stream>>>(cnt, off, bsum);
    k_scan2<<<1, 128, 0, stream>>>(bsum);
    k_scan3<<<nblk_n, 256, 0, stream>>>(off, bsum, cnt, dinv);
    k_fill<<<nblk_e, 256, 0, stream>>>(ei, off, fill, csr);
    k_gemm<<<(N_NODES + GM_ROWS - 1) / GM_ROWS, 256, 0, stream>>>(x, W, h);
    k_gather<<<(N_NODES + 3) / 4, 256, 0, stream>>>(csr, off, h, dinv, b, out);
    k_stats<<<512, 256, 0, stream>>>(out, stats);
    k_norm<<<(N_NODES * D + 255) / 256, 256, 0, stream>>>(out, stats, gamma, beta);
}

// Round 3
// 234.659 us; speedup vs baseline: 3.0123x; 1.2226x over previous
//
#include <hip/hip_runtime.h>
#include <hip/hip_bf16.h>

#define N_NODES 100000
#define N_EDGES 640000
#define D 128
#define BN_EPS 1e-5f
#define NB_SCAN 98  // ceil(100000/1024)

typedef __attribute__((ext_vector_type(8))) short short8;
typedef __attribute__((ext_vector_type(4))) float f32x4;

__device__ inline unsigned int f2bf(float f) {  // RNE float->bf16 (returns in low 16)
    unsigned int u = __builtin_bit_cast(unsigned int, f);
    return (u + 0x7FFFu + ((u >> 16) & 1u)) >> 16;
}
__device__ inline float bflo(unsigned int p) { return __builtin_bit_cast(float, p << 16); }
__device__ inline float bfhi(unsigned int p) { return __builtin_bit_cast(float, p & 0xFFFF0000u); }

// ---------------- zero counters ----------------
__global__ void k_zero(int* __restrict__ cnt, int* __restrict__ fill, float* __restrict__ stats) {
    int i = blockIdx.x * 256 + threadIdx.x;
    if (i < N_NODES) { cnt[i] = 0; fill[i] = 0; }
    if (i < 256) stats[i] = 0.0f;
}

// ---------------- count incoming edges per dst ----------------
__global__ void k_cnt(const int* __restrict__ ei, int* __restrict__ cnt) {
    int e = blockIdx.x * 256 + threadIdx.x;
    if (e < N_EDGES) atomicAdd(&cnt[ei[N_EDGES + e]], 1);
}

// ---------------- scan stage 1 ----------------
__global__ __launch_bounds__(1024) void k_scan1(const int* __restrict__ cnt,
                                                int* __restrict__ off,
                                                int* __restrict__ bsum) {
    __shared__ int s[1024];
    const int t = threadIdx.x;
    const int i = blockIdx.x * 1024 + t;
    const int v = (i < N_NODES) ? cnt[i] : 0;
    s[t] = v;
    __syncthreads();
    for (int d = 1; d < 1024; d <<= 1) {
        int u = (t >= d) ? s[t - d] : 0;
        __syncthreads();
        s[t] += u;
        __syncthreads();
    }
    if (i < N_NODES) off[i] = s[t] - v;
    if (t == 1023) bsum[blockIdx.x] = s[t];
}

// ---------------- scan stage 2 ----------------
__global__ __launch_bounds__(128) void k_scan2(int* __restrict__ bsum) {
    __shared__ int s[128];
    const int t = threadIdx.x;
    const int v = (t < NB_SCAN) ? bsum[t] : 0;
    s[t] = v;
    __syncthreads();
    for (int d = 1; d < 128; d <<= 1) {
        int u = (t >= d) ? s[t - d] : 0;
        __syncthreads();
        s[t] += u;
        __syncthreads();
    }
    if (t < NB_SCAN) bsum[t] = s[t] - v;
}

// ---------------- scan stage 3 + dinv ----------------
__global__ void k_scan3(int* __restrict__ off, const int* __restrict__ bsum,
                        const int* __restrict__ cnt, float* __restrict__ dinv) {
    const int i = blockIdx.x * 256 + threadIdx.x;
    if (i < N_NODES) {
        off[i] += bsum[i >> 10];
        dinv[i] = rsqrtf((float)(cnt[i] + 1));
    }
    if (i == 0) off[N_NODES] = N_EDGES;
}

// ---------------- fill CSR ----------------
__global__ void k_fill(const int* __restrict__ ei, const int* __restrict__ off,
                       int* __restrict__ fill, int* __restrict__ csr) {
    int e = blockIdx.x * 256 + threadIdx.x;
    if (e < N_EDGES) {
        int d = ei[N_EDGES + e];
        int slot = atomicAdd(&fill[d], 1);
        csr[off[d] + slot] = ei[e];
    }
}

// ---------------- convert x -> bf16 (packed pairs) ----------------
__global__ __launch_bounds__(256) void k_cvt(const float* __restrict__ x, uint4* __restrict__ xb) {
    const size_t i = (size_t)blockIdx.x * 256 + threadIdx.x;  // one uint4 = 8 bf16
    if (i >= (size_t)N_NODES * D / 8) return;
    const float4* xg = (const float4*)x;
    float4 a = xg[2 * i], c = xg[2 * i + 1];
    uint4 o;
    o.x = f2bf(a.x) | (f2bf(a.y) << 16);
    o.y = f2bf(a.z) | (f2bf(a.w) << 16);
    o.z = f2bf(c.x) | (f2bf(c.y) << 16);
    o.w = f2bf(c.z) | (f2bf(c.w) << 16);
    xb[i] = o;
}

// ---------------- convert + transpose W -> Wt bf16 [col][k] ----------------
__global__ __launch_bounds__(256) void k_cvtw(const float* __restrict__ W,
                                              unsigned short* __restrict__ Wt) {
    const int t = threadIdx.x;
    const int c = t >> 1;
    const int k0 = (t & 1) * 64;
    for (int k = 0; k < 64; ++k)
        Wt[c * D + k0 + k] = (unsigned short)f2bf(W[(size_t)(k0 + k) * D + c]);
}

// ---------------- gather on x (bf16): agg = x[n]*dinv^2 + sum x[s]*dinv[s]*dinv[n] ----------------
__global__ __launch_bounds__(256) void k_gather(const int* __restrict__ csr,
                                                const int* __restrict__ off,
                                                const unsigned int* __restrict__ xb,
                                                const float* __restrict__ dinv,
                                                unsigned int* __restrict__ agg) {
    const int t = threadIdx.x;
    const int lane = t & 63;
    const int n = blockIdx.x * 4 + (t >> 6);
    if (n >= N_NODES) return;

    const float di = dinv[n];
    const unsigned int hv = xb[(size_t)n * 64 + lane];
    const float dd = di * di;
    float ax = bflo(hv) * dd;
    float ay = bfhi(hv) * dd;

    const int j0 = off[n], j1 = off[n + 1];
    int j = j0;
    for (; j + 1 < j1; j += 2) {
        const int s0 = csr[j], s1 = csr[j + 1];
        const float n0 = dinv[s0] * di, n1 = dinv[s1] * di;
        const unsigned int v0 = xb[(size_t)s0 * 64 + lane];
        const unsigned int v1 = xb[(size_t)s1 * 64 + lane];
        ax = fmaf(bflo(v0), n0, ax);
        ay = fmaf(bfhi(v0), n0, ay);
        ax = fmaf(bflo(v1), n1, ax);
        ay = fmaf(bfhi(v1), n1, ay);
    }
    if (j < j1) {
        const int s0 = csr[j];
        const float n0 = dinv[s0] * di;
        const unsigned int v0 = xb[(size_t)s0 * 64 + lane];
        ax = fmaf(bflo(v0), n0, ax);
        ay = fmaf(bfhi(v0), n0, ay);
    }
    agg[(size_t)n * 64 + lane] = f2bf(ax) | (f2bf(ay) << 16);
}

// ---------------- MFMA GEMM: out = relu(agg @ W + b), fp32 out ----------------
// block: 256 thr = 4 waves; block covers 128 rows; wave w covers rows w*32..+31
__global__ __launch_bounds__(256) void k_mm(const unsigned short* __restrict__ agg,
                                            const unsigned short* __restrict__ Wt,
                                            const float* __restrict__ b,
                                            float* __restrict__ out) {
    const int t = threadIdx.x;
    const int w = t >> 6;
    const int l = t & 63;
    const int lr = l & 15;   // row (A) / col (B,D)
    const int lk = l >> 4;   // k-group (A,B) / row-group (D)
    const int r0 = blockIdx.x * 128 + w * 32;

    f32x4 acc[2][8];
#pragma unroll
    for (int rt = 0; rt < 2; ++rt)
#pragma unroll
        for (int ct = 0; ct < 8; ++ct) acc[rt][ct] = (f32x4)(0.0f);

#pragma unroll
    for (int kk = 0; kk < 4; ++kk) {
        short8 a[2];
#pragma unroll
        for (int rt = 0; rt < 2; ++rt) {
            int row = r0 + rt * 16 + lr;
            if (row >= N_NODES) row = N_NODES - 1;  // clamp (stores masked)
            a[rt] = *(const short8*)(agg + (size_t)row * D + kk * 32 + lk * 8);
        }
        short8 bb[8];
#pragma unroll
        for (int ct = 0; ct < 8; ++ct)
            bb[ct] = *(const short8*)(Wt + (size_t)(ct * 16 + lr) * D + kk * 32 + lk * 8);
#pragma unroll
        for (int rt = 0; rt < 2; ++rt)
#pragma unroll
            for (int ct = 0; ct < 8; ++ct)
                acc[rt][ct] = __builtin_amdgcn_mfma_f32_16x16x32_bf16(a[rt], bb[ct], acc[rt][ct], 0, 0, 0);
    }

#pragma unroll
    for (int ct = 0; ct < 8; ++ct) {
        const float bias = b[ct * 16 + lr];
#pragma unroll
        for (int rt = 0; rt < 2; ++rt) {
#pragma unroll
            for (int r = 0; r < 4; ++r) {
                const int row = r0 + rt * 16 + lk * 4 + r;
                if (row < N_NODES)
                    out[(size_t)row * D + ct * 16 + lr] = fmaxf(acc[rt][ct][r] + bias, 0.0f);
            }
        }
    }
}

// ---------------- BN stats (input already relu'd) ----------------
__global__ __launch_bounds__(256) void k_stats(const float* __restrict__ agg,
                                               float* __restrict__ stats) {
    const int t = threadIdx.x;
    const int c = t & 127;
    const int half = t >> 7;
    float s = 0.0f, s2 = 0.0f;
    for (int r = blockIdx.x * 2 + half; r < N_NODES; r += gridDim.x * 2) {
        float v = agg[(size_t)r * D + c];
        s += v;
        s2 = fmaf(v, v, s2);
    }
    __shared__ float ls[256], ls2[256];
    ls[t] = s; ls2[t] = s2;
    __syncthreads();
    if (t < 128) {
        atomicAdd(&stats[c], ls[t] + ls[t + 128]);
        atomicAdd(&stats[128 + c], ls2[t] + ls2[t + 128]);
    }
}

// ---------------- normalize in place, float4 ----------------
__global__ __launch_bounds__(256) void k_norm(float4* __restrict__ io,
                                              const float* __restrict__ stats,
                                              const float* __restrict__ gamma,
                                              const float* __restrict__ beta) {
    const size_t i = (size_t)blockIdx.x * 256 + threadIdx.x;
    if (i >= (size_t)N_NODES * 32) return;
    const int c0 = (int)(i & 31) * 4;
    const float inv_n = 1.0f / (float)N_NODES;
    float4 v = io[i];
    float* vp = (float*)&v;
#pragma unroll
    for (int j = 0; j < 4; ++j) {
        const int c = c0 + j;
        const float mean = stats[c] * inv_n;
        const float var = stats[128 + c] * inv_n - mean * mean;
        vp[j] = fmaf(gamma[c] * rsqrtf(var + BN_EPS), vp[j] - mean, beta[c]);
    }
    io[i] = v;
}

extern "C" void kernel_launch(void* const* d_in, const int* in_sizes, int n_in,
                              void* d_out, int out_size, void* d_ws, size_t ws_size,
                              hipStream_t stream) {
    const float* x     = (const float*)d_in[0];
    const int*   ei    = (const int*)d_in[1];
    const float* W     = (const float*)d_in[2];
    const float* b     = (const float*)d_in[3];
    const float* gamma = (const float*)d_in[4];
    const float* beta  = (const float*)d_in[5];
    float* out = (float*)d_out;

    char* ws = (char*)d_ws;
    int*            cnt   = (int*)(ws + 0);                    // 400 KB
    int*            fill  = (int*)(ws + (512u << 10));         // 400 KB
    int*            off   = (int*)(ws + (1024u << 10));        // 400 KB + 4
    int*            bsum  = (int*)(ws + (1536u << 10));        // 392 B
    float*          dinv  = (float*)(ws + (1792u << 10));      // 400 KB
    float*          stats = (float*)(ws + (2304u << 10));      // 1 KB
    unsigned short* Wt    = (unsigned short*)(ws + (2432u << 10));  // 32 KB
    int*            csr   = (int*)(ws + (2560u << 10));        // 2.56 MB
    unsigned int*   xb    = (unsigned int*)(ws + (6144u << 10));    // 25.6 MB
    unsigned int*   agg   = (unsigned int*)(ws + (32768u << 10));   // 25.6 MB

    const int nblk_n = (N_NODES + 255) / 256;   // 391
    const int nblk_e = (N_EDGES + 255) / 256;   // 2500

    k_zero<<<nblk_n, 256, 0, stream>>>(cnt, fill, stats);
    k_cnt<<<nblk_e, 256, 0, stream>>>(ei, cnt);
    k_scan1<<<NB_SCAN, 1024, 0, stream>>>(cnt, off, bsum);
    k_scan2<<<1, 128, 0, stream>>>(bsum);
    k_scan3<<<nblk_n, 256, 0, stream>>>(off, bsum, cnt, dinv);
    k_fill<<<nblk_e, 256, 0, stream>>>(ei, off, fill, csr);
    k_cvt<<<(N_NODES * D / 8 + 255) / 256, 256, 0, stream>>>(x, (uint4*)xb);
    k_cvtw<<<1, 256, 0, stream>>>(W, Wt);
    k_gather<<<(N_NODES + 3) / 4, 256, 0, stream>>>(csr, off, xb, dinv, agg);
    k_mm<<<(N_NODES + 127) / 128, 256, 0, stream>>>((const unsigned short*)agg, Wt, b, out);
    k_stats<<<512, 256, 0, stream>>>(out, stats);
    k_norm<<<(N_NODES * 32 + 255) / 256, 256, 0, stream>>>((float4*)out, stats, gamma, beta);
}

// Round 4
// 198.620 us; speedup vs baseline: 3.5588x; 1.1814x over previous
//
#include <hip/hip_runtime.h>
#include <hip/hip_bf16.h>

#define N_NODES 100000
#define N_EDGES 640000
#define D 128
#define BN_EPS 1e-5f
#define NB_SCAN 98   // ceil(100000/1024)
#define NB_CVT 6250  // N*D/8/256

typedef __attribute__((ext_vector_type(8))) short short8;
typedef __attribute__((ext_vector_type(4))) float f32x4;

__device__ inline unsigned int f2bf(float f) {  // RNE float->bf16 (low 16)
    unsigned int u = __builtin_bit_cast(unsigned int, f);
    return (u + 0x7FFFu + ((u >> 16) & 1u)) >> 16;
}
__device__ inline float bflo(unsigned int p) { return __builtin_bit_cast(float, p << 16); }
__device__ inline float bfhi(unsigned int p) { return __builtin_bit_cast(float, p & 0xFFFF0000u); }

// ---------------- zero cnt + stats ----------------
__global__ void k_zero(int* __restrict__ cnt, float* __restrict__ stats) {
    int i = blockIdx.x * 256 + threadIdx.x;
    if (i < N_NODES) cnt[i] = 0;
    if (i < 256) stats[i] = 0.0f;
}

// ---------------- count incoming edges per dst ----------------
__global__ void k_cnt(const int* __restrict__ ei, int* __restrict__ cnt) {
    int e = blockIdx.x * 256 + threadIdx.x;
    if (e < N_EDGES) atomicAdd(&cnt[ei[N_EDGES + e]], 1);
}

// ---------------- scan stage 1 ----------------
__global__ __launch_bounds__(1024) void k_scan1(const int* __restrict__ cnt,
                                                int* __restrict__ off,
                                                int* __restrict__ bsum) {
    __shared__ int s[1024];
    const int t = threadIdx.x;
    const int i = blockIdx.x * 1024 + t;
    const int v = (i < N_NODES) ? cnt[i] : 0;
    s[t] = v;
    __syncthreads();
    for (int d = 1; d < 1024; d <<= 1) {
        int u = (t >= d) ? s[t - d] : 0;
        __syncthreads();
        s[t] += u;
        __syncthreads();
    }
    if (i < N_NODES) off[i] = s[t] - v;
    if (t == 1023) bsum[blockIdx.x] = s[t];
}

// ---------------- scan stage 2 ----------------
__global__ __launch_bounds__(128) void k_scan2(int* __restrict__ bsum) {
    __shared__ int s[128];
    const int t = threadIdx.x;
    const int v = (t < NB_SCAN) ? bsum[t] : 0;
    s[t] = v;
    __syncthreads();
    for (int d = 1; d < 128; d <<= 1) {
        int u = (t >= d) ? s[t - d] : 0;
        __syncthreads();
        s[t] += u;
        __syncthreads();
    }
    if (t < NB_SCAN) bsum[t] = s[t] - v;
}

// ---------------- scan stage 3 + dinv ----------------
__global__ void k_scan3(int* __restrict__ off, const int* __restrict__ bsum,
                        const int* __restrict__ cnt, float* __restrict__ dinv) {
    const int i = blockIdx.x * 256 + threadIdx.x;
    if (i < N_NODES) {
        off[i] += bsum[i >> 10];
        dinv[i] = rsqrtf((float)(cnt[i] + 1));
    }
    if (i == 0) off[N_NODES] = N_EDGES;
}

// ---------------- fill CSR (cnt doubles as decrementing cursor) ----------------
__global__ void k_fill(const int* __restrict__ ei, const int* __restrict__ off,
                       int* __restrict__ cnt, int* __restrict__ csr) {
    int e = blockIdx.x * 256 + threadIdx.x;
    if (e < N_EDGES) {
        int d = ei[N_EDGES + e];
        int slot = atomicAdd(&cnt[d], -1) - 1;  // deg-1 .. 0
        csr[off[d] + slot] = ei[e];
    }
}

// ---------------- convert x -> bf16 pairs AND W -> Wt bf16 [col][k] ----------------
__global__ __launch_bounds__(256) void k_cvt(const float* __restrict__ x, uint4* __restrict__ xb,
                                             const float* __restrict__ W,
                                             unsigned short* __restrict__ Wt) {
    const int bid = blockIdx.x;
    const int t = threadIdx.x;
    if (bid < NB_CVT) {
        const size_t i = (size_t)bid * 256 + t;  // one uint4 = 8 bf16
        const float4* xg = (const float4*)x;
        float4 a = xg[2 * i], c = xg[2 * i + 1];
        uint4 o;
        o.x = f2bf(a.x) | (f2bf(a.y) << 16);
        o.y = f2bf(a.z) | (f2bf(a.w) << 16);
        o.z = f2bf(c.x) | (f2bf(c.y) << 16);
        o.w = f2bf(c.z) | (f2bf(c.w) << 16);
        xb[i] = o;
    } else {
        const int i = (bid - NB_CVT) * 256 + t;  // i = k*128 + c over 16384
        const int c = i & 127, k = i >> 7;
        Wt[(size_t)c * D + k] = (unsigned short)f2bf(W[i]);
    }
}

// ---------------- gather (pipelined): agg = x[n]*dinv^2 + sum x[s]*dinv[s]*dinv[n] ----------------
__global__ __launch_bounds__(256) void k_gather(const int* __restrict__ csr,
                                                const int* __restrict__ off,
                                                const unsigned int* __restrict__ xb,
                                                const float* __restrict__ dinv,
                                                unsigned int* __restrict__ agg) {
    const int t = threadIdx.x;
    const int lane = t & 63;
    const int n = blockIdx.x * 4 + (t >> 6);
    if (n >= N_NODES) return;

    const float di = dinv[n];
    const unsigned int hv = xb[(size_t)n * 64 + lane];
    const float dd = di * di;
    float ax = bflo(hv) * dd;
    float ay = bfhi(hv) * dd;

    const int j0 = off[n], j1 = off[n + 1];
    for (int base = j0; base < j1; base += 64) {
        int m = j1 - base; if (m > 64) m = 64;
        // wave-parallel preload of indices + edge norms (one latency for all)
        int s_l = 0; float f_l = 0.0f;
        if (base + lane < j1) {
            s_l = csr[base + lane];
            f_l = dinv[s_l] * di;
        }
        int k = 0;
        for (; k + 4 <= m; k += 4) {
            const int s0 = __shfl(s_l, k),     s1 = __shfl(s_l, k + 1);
            const int s2 = __shfl(s_l, k + 2), s3 = __shfl(s_l, k + 3);
            const float f0 = __shfl(f_l, k),     f1 = __shfl(f_l, k + 1);
            const float f2 = __shfl(f_l, k + 2), f3 = __shfl(f_l, k + 3);
            const unsigned int v0 = xb[(size_t)s0 * 64 + lane];
            const unsigned int v1 = xb[(size_t)s1 * 64 + lane];
            const unsigned int v2 = xb[(size_t)s2 * 64 + lane];
            const unsigned int v3 = xb[(size_t)s3 * 64 + lane];
            ax = fmaf(bflo(v0), f0, ax); ay = fmaf(bfhi(v0), f0, ay);
            ax = fmaf(bflo(v1), f1, ax); ay = fmaf(bfhi(v1), f1, ay);
            ax = fmaf(bflo(v2), f2, ax); ay = fmaf(bfhi(v2), f2, ay);
            ax = fmaf(bflo(v3), f3, ax); ay = fmaf(bfhi(v3), f3, ay);
        }
        for (; k < m; ++k) {
            const int s0 = __shfl(s_l, k);
            const float f0 = __shfl(f_l, k);
            const unsigned int v0 = xb[(size_t)s0 * 64 + lane];
            ax = fmaf(bflo(v0), f0, ax); ay = fmaf(bfhi(v0), f0, ay);
        }
    }
    agg[(size_t)n * 64 + lane] = f2bf(ax) | (f2bf(ay) << 16);
}

// ---------------- MFMA GEMM: out = relu(agg @ W + b); fused BN-stats partials ----------------
__global__ __launch_bounds__(256) void k_mm(const unsigned short* __restrict__ agg,
                                            const unsigned short* __restrict__ Wt,
                                            const float* __restrict__ b,
                                            float* __restrict__ out,
                                            float* __restrict__ stats) {
    const int t = threadIdx.x;
    const int w = t >> 6;
    const int l = t & 63;
    const int lr = l & 15;
    const int lk = l >> 4;
    const int r0 = blockIdx.x * 128 + w * 32;

    f32x4 acc[2][8];
#pragma unroll
    for (int rt = 0; rt < 2; ++rt)
#pragma unroll
        for (int ct = 0; ct < 8; ++ct) acc[rt][ct] = (f32x4)(0.0f);

#pragma unroll
    for (int kk = 0; kk < 4; ++kk) {
        short8 a[2];
#pragma unroll
        for (int rt = 0; rt < 2; ++rt) {
            int row = r0 + rt * 16 + lr;
            if (row >= N_NODES) row = N_NODES - 1;  // clamp (stores masked)
            a[rt] = *(const short8*)(agg + (size_t)row * D + kk * 32 + lk * 8);
        }
        short8 bb[8];
#pragma unroll
        for (int ct = 0; ct < 8; ++ct)
            bb[ct] = *(const short8*)(Wt + (size_t)(ct * 16 + lr) * D + kk * 32 + lk * 8);
#pragma unroll
        for (int rt = 0; rt < 2; ++rt)
#pragma unroll
            for (int ct = 0; ct < 8; ++ct)
                acc[rt][ct] = __builtin_amdgcn_mfma_f32_16x16x32_bf16(a[rt], bb[ct], acc[rt][ct], 0, 0, 0);
    }

    __shared__ float lsum[4][128];
    __shared__ float lsq[4][128];
    float s[8], s2[8];
#pragma unroll
    for (int ct = 0; ct < 8; ++ct) { s[ct] = 0.0f; s2[ct] = 0.0f; }

#pragma unroll
    for (int ct = 0; ct < 8; ++ct) {
        const float bias = b[ct * 16 + lr];
#pragma unroll
        for (int rt = 0; rt < 2; ++rt) {
#pragma unroll
            for (int r = 0; r < 4; ++r) {
                const int row = r0 + rt * 16 + lk * 4 + r;
                const float v = fmaxf(acc[rt][ct][r] + bias, 0.0f);
                if (row < N_NODES) {
                    out[(size_t)row * D + ct * 16 + lr] = v;
                    s[ct] += v;
                    s2[ct] = fmaf(v, v, s2[ct]);
                }
            }
        }
    }
#pragma unroll
    for (int ct = 0; ct < 8; ++ct) {
        s[ct]  += __shfl_xor(s[ct], 16);  s[ct]  += __shfl_xor(s[ct], 32);
        s2[ct] += __shfl_xor(s2[ct], 16); s2[ct] += __shfl_xor(s2[ct], 32);
    }
    if (l < 16) {
#pragma unroll
        for (int ct = 0; ct < 8; ++ct) {
            lsum[w][ct * 16 + lr] = s[ct];
            lsq[w][ct * 16 + lr]  = s2[ct];
        }
    }
    __syncthreads();
    if (t < 128) {
        atomicAdd(&stats[t],       lsum[0][t] + lsum[1][t] + lsum[2][t] + lsum[3][t]);
        atomicAdd(&stats[128 + t], lsq[0][t] + lsq[1][t] + lsq[2][t] + lsq[3][t]);
    }
}

// ---------------- normalize in place, float4 ----------------
__global__ __launch_bounds__(256) void k_norm(float4* __restrict__ io,
                                              const float* __restrict__ stats,
                                              const float* __restrict__ gamma,
                                              const float* __restrict__ beta) {
    const size_t i = (size_t)blockIdx.x * 256 + threadIdx.x;
    if (i >= (size_t)N_NODES * 32) return;
    const int c0 = (int)(i & 31) * 4;
    const float inv_n = 1.0f / (float)N_NODES;
    float4 v = io[i];
    float* vp = (float*)&v;
#pragma unroll
    for (int j = 0; j < 4; ++j) {
        const int c = c0 + j;
        const float mean = stats[c] * inv_n;
        const float var = stats[128 + c] * inv_n - mean * mean;
        vp[j] = fmaf(gamma[c] * rsqrtf(var + BN_EPS), vp[j] - mean, beta[c]);
    }
    io[i] = v;
}

extern "C" void kernel_launch(void* const* d_in, const int* in_sizes, int n_in,
                              void* d_out, int out_size, void* d_ws, size_t ws_size,
                              hipStream_t stream) {
    const float* x     = (const float*)d_in[0];
    const int*   ei    = (const int*)d_in[1];
    const float* W     = (const float*)d_in[2];
    const float* b     = (const float*)d_in[3];
    const float* gamma = (const float*)d_in[4];
    const float* beta  = (const float*)d_in[5];
    float* out = (float*)d_out;

    char* ws = (char*)d_ws;
    int*            cnt   = (int*)(ws + 0);                         // 400 KB
    int*            off   = (int*)(ws + (1024u << 10));             // 400 KB + 4
    int*            bsum  = (int*)(ws + (1536u << 10));             // 392 B
    float*          dinv  = (float*)(ws + (1792u << 10));           // 400 KB
    float*          stats = (float*)(ws + (2304u << 10));           // 1 KB
    unsigned short* Wt    = (unsigned short*)(ws + (2432u << 10));  // 32 KB
    int*            csr   = (int*)(ws + (2560u << 10));             // 2.56 MB
    unsigned int*   xb    = (unsigned int*)(ws + (6144u << 10));    // 25.6 MB
    unsigned int*   agg   = (unsigned int*)(ws + (32768u << 10));   // 25.6 MB

    const int nblk_n = (N_NODES + 255) / 256;   // 391
    const int nblk_e = (N_EDGES + 255) / 256;   // 2500

    k_zero<<<nblk_n, 256, 0, stream>>>(cnt, stats);
    k_cnt<<<nblk_e, 256, 0, stream>>>(ei, cnt);
    k_scan1<<<NB_SCAN, 1024, 0, stream>>>(cnt, off, bsum);
    k_scan2<<<1, 128, 0, stream>>>(bsum);
    k_scan3<<<nblk_n, 256, 0, stream>>>(off, bsum, cnt, dinv);
    k_fill<<<nblk_e, 256, 0, stream>>>(ei, off, cnt, csr);
    k_cvt<<<NB_CVT + 64, 256, 0, stream>>>(x, (uint4*)xb, W, Wt);
    k_gather<<<(N_NODES + 3) / 4, 256, 0, stream>>>(csr, off, xb, dinv, agg);
    k_mm<<<(N_NODES + 127) / 128, 256, 0, stream>>>((const unsigned short*)agg, Wt, b, out, stats);
    k_norm<<<(N_NODES * 32 + 255) / 256, 256, 0, stream>>>((float4*)out, stats, gamma, beta);
}

// Round 5
// 185.641 us; speedup vs baseline: 3.8076x; 1.0699x over previous
//
#include <hip/hip_runtime.h>
#include <hip/hip_bf16.h>

#define N_NODES 100000
#define N_EDGES 640000
#define D 128
#define BN_EPS 1e-5f
#define NB_SCAN 98   // ceil(100000/1024)
#define NB_CVT 6250  // N*D/8/256
#define NREP 64      // stats replication factor

typedef __attribute__((ext_vector_type(8))) short short8;
typedef __attribute__((ext_vector_type(4))) float f32x4;

__device__ inline unsigned int f2bf(float f) {  // RNE float->bf16 (low 16)
    unsigned int u = __builtin_bit_cast(unsigned int, f);
    return (u + 0x7FFFu + ((u >> 16) & 1u)) >> 16;
}
__device__ inline float bflo(unsigned int p) { return __builtin_bit_cast(float, p << 16); }
__device__ inline float bfhi(unsigned int p) { return __builtin_bit_cast(float, p & 0xFFFF0000u); }

// ---------------- zero cnt + replicated stats ----------------
__global__ void k_zero(int* __restrict__ cnt, float* __restrict__ rep) {
    int i = blockIdx.x * 256 + threadIdx.x;
    if (i < N_NODES) cnt[i] = 0;
    if (i < NREP * 256) rep[i] = 0.0f;
}

// ---------------- count incoming edges per dst ----------------
__global__ void k_cnt(const int* __restrict__ ei, int* __restrict__ cnt) {
    int e = blockIdx.x * 256 + threadIdx.x;
    if (e < N_EDGES) atomicAdd(&cnt[ei[N_EDGES + e]], 1);
}

// ---------------- scan stage 1 ----------------
__global__ __launch_bounds__(1024) void k_scan1(const int* __restrict__ cnt,
                                                int* __restrict__ off,
                                                int* __restrict__ bsum) {
    __shared__ int s[1024];
    const int t = threadIdx.x;
    const int i = blockIdx.x * 1024 + t;
    const int v = (i < N_NODES) ? cnt[i] : 0;
    s[t] = v;
    __syncthreads();
    for (int d = 1; d < 1024; d <<= 1) {
        int u = (t >= d) ? s[t - d] : 0;
        __syncthreads();
        s[t] += u;
        __syncthreads();
    }
    if (i < N_NODES) off[i] = s[t] - v;
    if (t == 1023) bsum[blockIdx.x] = s[t];
}

// ---------------- scan stage 2 ----------------
__global__ __launch_bounds__(128) void k_scan2(int* __restrict__ bsum) {
    __shared__ int s[128];
    const int t = threadIdx.x;
    const int v = (t < NB_SCAN) ? bsum[t] : 0;
    s[t] = v;
    __syncthreads();
    for (int d = 1; d < 128; d <<= 1) {
        int u = (t >= d) ? s[t - d] : 0;
        __syncthreads();
        s[t] += u;
        __syncthreads();
    }
    if (t < NB_SCAN) bsum[t] = s[t] - v;
}

// ---------------- scan stage 3 + dinv ----------------
__global__ void k_scan3(int* __restrict__ off, const int* __restrict__ bsum,
                        const int* __restrict__ cnt, float* __restrict__ dinv) {
    const int i = blockIdx.x * 256 + threadIdx.x;
    if (i < N_NODES) {
        off[i] += bsum[i >> 10];
        dinv[i] = rsqrtf((float)(cnt[i] + 1));
    }
    if (i == 0) off[N_NODES] = N_EDGES;
}

// ---------------- fill CSR (cnt doubles as decrementing cursor) ----------------
__global__ void k_fill(const int* __restrict__ ei, const int* __restrict__ off,
                       int* __restrict__ cnt, int* __restrict__ csr) {
    int e = blockIdx.x * 256 + threadIdx.x;
    if (e < N_EDGES) {
        int d = ei[N_EDGES + e];
        int slot = atomicAdd(&cnt[d], -1) - 1;  // deg-1 .. 0
        csr[off[d] + slot] = ei[e];
    }
}

// ---------------- convert x -> bf16 pairs AND W -> Wt bf16 [col][k] ----------------
__global__ __launch_bounds__(256) void k_cvt(const float* __restrict__ x, uint4* __restrict__ xb,
                                             const float* __restrict__ W,
                                             unsigned short* __restrict__ Wt) {
    const int bid = blockIdx.x;
    const int t = threadIdx.x;
    if (bid < NB_CVT) {
        const size_t i = (size_t)bid * 256 + t;  // one uint4 = 8 bf16
        const float4* xg = (const float4*)x;
        float4 a = xg[2 * i], c = xg[2 * i + 1];
        uint4 o;
        o.x = f2bf(a.x) | (f2bf(a.y) << 16);
        o.y = f2bf(a.z) | (f2bf(a.w) << 16);
        o.z = f2bf(c.x) | (f2bf(c.y) << 16);
        o.w = f2bf(c.z) | (f2bf(c.w) << 16);
        xb[i] = o;
    } else {
        const int i = (bid - NB_CVT) * 256 + t;  // i = k*128 + c over 16384
        const int c = i & 127, k = i >> 7;
        Wt[(size_t)c * D + k] = (unsigned short)f2bf(W[i]);
    }
}

// ---------------- gather (pipelined): agg = x[n]*dinv^2 + sum x[s]*dinv[s]*dinv[n] ----------------
__global__ __launch_bounds__(256) void k_gather(const int* __restrict__ csr,
                                                const int* __restrict__ off,
                                                const unsigned int* __restrict__ xb,
                                                const float* __restrict__ dinv,
                                                unsigned int* __restrict__ agg) {
    const int t = threadIdx.x;
    const int lane = t & 63;
    const int n = blockIdx.x * 4 + (t >> 6);
    if (n >= N_NODES) return;

    const float di = dinv[n];
    const unsigned int hv = xb[(size_t)n * 64 + lane];
    const float dd = di * di;
    float ax = bflo(hv) * dd;
    float ay = bfhi(hv) * dd;

    const int j0 = off[n], j1 = off[n + 1];
    for (int base = j0; base < j1; base += 64) {
        int m = j1 - base; if (m > 64) m = 64;
        int s_l = 0; float f_l = 0.0f;
        if (base + lane < j1) {
            s_l = csr[base + lane];
            f_l = dinv[s_l] * di;
        }
        int k = 0;
        for (; k + 4 <= m; k += 4) {
            const int s0 = __shfl(s_l, k),     s1 = __shfl(s_l, k + 1);
            const int s2 = __shfl(s_l, k + 2), s3 = __shfl(s_l, k + 3);
            const float f0 = __shfl(f_l, k),     f1 = __shfl(f_l, k + 1);
            const float f2 = __shfl(f_l, k + 2), f3 = __shfl(f_l, k + 3);
            const unsigned int v0 = xb[(size_t)s0 * 64 + lane];
            const unsigned int v1 = xb[(size_t)s1 * 64 + lane];
            const unsigned int v2 = xb[(size_t)s2 * 64 + lane];
            const unsigned int v3 = xb[(size_t)s3 * 64 + lane];
            ax = fmaf(bflo(v0), f0, ax); ay = fmaf(bfhi(v0), f0, ay);
            ax = fmaf(bflo(v1), f1, ax); ay = fmaf(bfhi(v1), f1, ay);
            ax = fmaf(bflo(v2), f2, ax); ay = fmaf(bfhi(v2), f2, ay);
            ax = fmaf(bflo(v3), f3, ax); ay = fmaf(bfhi(v3), f3, ay);
        }
        for (; k < m; ++k) {
            const int s0 = __shfl(s_l, k);
            const float f0 = __shfl(f_l, k);
            const unsigned int v0 = xb[(size_t)s0 * 64 + lane];
            ax = fmaf(bflo(v0), f0, ax); ay = fmaf(bfhi(v0), f0, ay);
        }
    }
    agg[(size_t)n * 64 + lane] = f2bf(ax) | (f2bf(ay) << 16);
}

// ---------------- MFMA GEMM: out = relu(agg @ W + b); BN-stats partials -> replicated atomics ----------------
__global__ __launch_bounds__(256) void k_mm(const unsigned short* __restrict__ agg,
                                            const unsigned short* __restrict__ Wt,
                                            const float* __restrict__ b,
                                            float* __restrict__ out,
                                            float* __restrict__ rep) {
    const int t = threadIdx.x;
    const int w = t >> 6;
    const int l = t & 63;
    const int lr = l & 15;
    const int lk = l >> 4;
    const int r0 = blockIdx.x * 128 + w * 32;

    f32x4 acc[2][8];
#pragma unroll
    for (int rt = 0; rt < 2; ++rt)
#pragma unroll
        for (int ct = 0; ct < 8; ++ct) acc[rt][ct] = (f32x4)(0.0f);

#pragma unroll
    for (int kk = 0; kk < 4; ++kk) {
        short8 a[2];
#pragma unroll
        for (int rt = 0; rt < 2; ++rt) {
            int row = r0 + rt * 16 + lr;
            if (row >= N_NODES) row = N_NODES - 1;  // clamp (stores masked)
            a[rt] = *(const short8*)(agg + (size_t)row * D + kk * 32 + lk * 8);
        }
        short8 bb[8];
#pragma unroll
        for (int ct = 0; ct < 8; ++ct)
            bb[ct] = *(const short8*)(Wt + (size_t)(ct * 16 + lr) * D + kk * 32 + lk * 8);
#pragma unroll
        for (int rt = 0; rt < 2; ++rt)
#pragma unroll
            for (int ct = 0; ct < 8; ++ct)
                acc[rt][ct] = __builtin_amdgcn_mfma_f32_16x16x32_bf16(a[rt], bb[ct], acc[rt][ct], 0, 0, 0);
    }

    __shared__ float lsum[4][128];
    __shared__ float lsq[4][128];
    float s[8], s2[8];
#pragma unroll
    for (int ct = 0; ct < 8; ++ct) { s[ct] = 0.0f; s2[ct] = 0.0f; }

#pragma unroll
    for (int ct = 0; ct < 8; ++ct) {
        const float bias = b[ct * 16 + lr];
#pragma unroll
        for (int rt = 0; rt < 2; ++rt) {
#pragma unroll
            for (int r = 0; r < 4; ++r) {
                const int row = r0 + rt * 16 + lk * 4 + r;
                const float v = fmaxf(acc[rt][ct][r] + bias, 0.0f);
                if (row < N_NODES) {
                    out[(size_t)row * D + ct * 16 + lr] = v;
                    s[ct] += v;
                    s2[ct] = fmaf(v, v, s2[ct]);
                }
            }
        }
    }
#pragma unroll
    for (int ct = 0; ct < 8; ++ct) {
        s[ct]  += __shfl_xor(s[ct], 16);  s[ct]  += __shfl_xor(s[ct], 32);
        s2[ct] += __shfl_xor(s2[ct], 16); s2[ct] += __shfl_xor(s2[ct], 32);
    }
    if (l < 16) {
#pragma unroll
        for (int ct = 0; ct < 8; ++ct) {
            lsum[w][ct * 16 + lr] = s[ct];
            lsq[w][ct * 16 + lr]  = s2[ct];
        }
    }
    __syncthreads();
    if (t < 128) {
        float* r = rep + (blockIdx.x & (NREP - 1)) * 256;
        atomicAdd(&r[t],       lsum[0][t] + lsum[1][t] + lsum[2][t] + lsum[3][t]);
        atomicAdd(&r[128 + t], lsq[0][t] + lsq[1][t] + lsq[2][t] + lsq[3][t]);
    }
}

// ---------------- collapse replicated stats ----------------
__global__ __launch_bounds__(256) void k_red(const float* __restrict__ rep,
                                             float* __restrict__ stats) {
    const int t = threadIdx.x;
    float s = 0.0f;
    for (int r = 0; r < NREP; ++r) s += rep[r * 256 + t];
    stats[t] = s;
}

// ---------------- normalize in place, float4 ----------------
__global__ __launch_bounds__(256) void k_norm(float4* __restrict__ io,
                                              const float* __restrict__ stats,
                                              const float* __restrict__ gamma,
                                              const float* __restrict__ beta) {
    const size_t i = (size_t)blockIdx.x * 256 + threadIdx.x;
    if (i >= (size_t)N_NODES * 32) return;
    const int c0 = (int)(i & 31) * 4;
    const float inv_n = 1.0f / (float)N_NODES;
    float4 v = io[i];
    float* vp = (float*)&v;
#pragma unroll
    for (int j = 0; j < 4; ++j) {
        const int c = c0 + j;
        const float mean = stats[c] * inv_n;
        const float var = stats[128 + c] * inv_n - mean * mean;
        vp[j] = fmaf(gamma[c] * rsqrtf(var + BN_EPS), vp[j] - mean, beta[c]);
    }
    io[i] = v;
}

extern "C" void kernel_launch(void* const* d_in, const int* in_sizes, int n_in,
                              void* d_out, int out_size, void* d_ws, size_t ws_size,
                              hipStream_t stream) {
    const float* x     = (const float*)d_in[0];
    const int*   ei    = (const int*)d_in[1];
    const float* W     = (const float*)d_in[2];
    const float* b     = (const float*)d_in[3];
    const float* gamma = (const float*)d_in[4];
    const float* beta  = (const float*)d_in[5];
    float* out = (float*)d_out;

    char* ws = (char*)d_ws;
    int*            cnt   = (int*)(ws + 0);                         // 400 KB
    int*            off   = (int*)(ws + (1024u << 10));             // 400 KB + 4
    int*            bsum  = (int*)(ws + (1536u << 10));             // 392 B
    float*          dinv  = (float*)(ws + (1792u << 10));           // 400 KB
    float*          stats = (float*)(ws + (2304u << 10));           // 1 KB
    float*          rep   = (float*)(ws + (2368u << 10));           // 64 KB
    unsigned short* Wt    = (unsigned short*)(ws + (2432u << 10));  // 32 KB
    int*            csr   = (int*)(ws + (2560u << 10));             // 2.56 MB
    unsigned int*   xb    = (unsigned int*)(ws + (6144u << 10));    // 25.6 MB
    unsigned int*   agg   = (unsigned int*)(ws + (32768u << 10));   // 25.6 MB

    const int nblk_n = (N_NODES + 255) / 256;   // 391
    const int nblk_e = (N_EDGES + 255) / 256;   // 2500

    k_zero<<<nblk_n, 256, 0, stream>>>(cnt, rep);
    k_cnt<<<nblk_e, 256, 0, stream>>>(ei, cnt);
    k_scan1<<<NB_SCAN, 1024, 0, stream>>>(cnt, off, bsum);
    k_scan2<<<1, 128, 0, stream>>>(bsum);
    k_scan3<<<nblk_n, 256, 0, stream>>>(off, bsum, cnt, dinv);
    k_fill<<<nblk_e, 256, 0, stream>>>(ei, off, cnt, csr);
    k_cvt<<<NB_CVT + 64, 256, 0, stream>>>(x, (uint4*)xb, W, Wt);
    k_gather<<<(N_NODES + 3) / 4, 256, 0, stream>>>(csr, off, xb, dinv, agg);
    k_mm<<<(N_NODES + 127) / 128, 256, 0, stream>>>((const unsigned short*)agg, Wt, b, out, rep);
    k_red<<<1, 256, 0, stream>>>(rep, stats);
    k_norm<<<(N_NODES * 32 + 255) / 256, 256, 0, stream>>>((float4*)out, stats, gamma, beta);
}